// Round 6
// baseline (276.681 us; speedup 1.0000x reference)
//
#include <hip/hip_runtime.h>

#define THRESH 0.05f

typedef __attribute__((ext_vector_type(4)))  int   int32x4;
typedef __attribute__((ext_vector_type(16))) int   int32x16;
typedef __attribute__((ext_vector_type(4)))  float floatx4;

// ---------------------------------------------------------------------------
// Kernel 1: quantize weight [1024,1024] fp32 -> int8 {-1,0,+1} in FRAGMENT
// ORDER for the mfma_i32_32x32x32_i8 B-operand:
//   1 KB block per (nb,k):  wqf[((nb*32 + k)*64 + lane)*16 + byte]
//   lane l supplies w[col = nb*32 + (l&31)][k*32 + (l>>5)*16 .. +16)
// (unchanged -- verified absmax 0 in rounds 0/1/3/4/5.)
// ---------------------------------------------------------------------------
__global__ __launch_bounds__(256) void quant_w_kernel(const float* __restrict__ w,
                                                      signed char* __restrict__ wqf) {
    int c = blockIdx.x * 256 + threadIdx.x;   // 16-byte chunk id, 0..65535
    int l  = c & 63;
    int k  = (c >> 6) & 31;
    int nb = c >> 11;
    int col   = nb * 32 + (l & 31);
    int kbase = k * 32 + (l >> 5) * 16;
    const float* src = w + col * 1024 + kbase;
    signed char q[16];
    #pragma unroll
    for (int j = 0; j < 4; ++j) {
        float4 f = *(const float4*)(src + j * 4);
        q[j * 4 + 0] = (signed char)((f.x >= THRESH) - (f.x <= -THRESH));
        q[j * 4 + 1] = (signed char)((f.y >= THRESH) - (f.y <= -THRESH));
        q[j * 4 + 2] = (signed char)((f.z >= THRESH) - (f.z <= -THRESH));
        q[j * 4 + 3] = (signed char)((f.w >= THRESH) - (f.w <= -THRESH));
    }
    *(int32x4*)(wqf + (size_t)c * 16) = *(const int32x4*)q;
}

// ---------------------------------------------------------------------------
// Kernel 2: 64-row slab ternary GEMM, 32x32x32 i8 MFMA.
// Block = 512 threads (8 waves), 64 KB LDS, grid 512 -> 2 blocks/CU,
// 16 waves/CU.
// vs round 5 (92.5 us, traffic clean, ~40 us exposed L2 latency): the
// single-buffered burst couldn't issue burst n+1 until burst n's MFMAs all
// issued -> each of 16 bursts/wave exposed ~250 cyc of L2 latency. Fix:
// PING-PONG double-buffered B, 4-deep per buffer (bA[4]/bB[4] = 32 VGPR
// TOTAL -- bounded, unlike round 4's rolling refill which doubled live
// ranges and spilled). Each step issues 4 loads into the idle buffer, then
// MFMAs the ready one -> compiler emits counted vmcnt(4), never drains
// (T4). Pipeline runs across ot boundaries (last step prefetches next
// tile's first burst; it stays in flight across the epilogue stores) and
// the first burst issues BEFORE __syncthreads (B independent of LDS).
// Kept: 64-row slab (512 MB B L2 traffic), fragment-order conflict-free
// LDS (block (k,ri) at (k*2+ri)*1024, slot = lane^(k&7)), unswapped
// epilogue (WRITE_SIZE = ideal 131 MB). Regs: 32 acc + 32 B + ~28 = ~92.
// ---------------------------------------------------------------------------
#define LOADB(buf, base_ptr, kb) do {                                          \
    _Pragma("unroll")                                                          \
    for (int j = 0; j < 4; ++j)                                                \
        buf[j] = *(const int32x4*)((base_ptr) + (size_t)((kb) + j) * 1024);    \
    __builtin_amdgcn_sched_barrier(0);                                         \
} while (0)

#define COMPB(buf, kb) do {                                                    \
    _Pragma("unroll")                                                          \
    for (int j = 0; j < 4; ++j) {                                              \
        const int k_  = (kb) + j;                                              \
        const int sl_ = (lane ^ (k_ & 7)) * 16;                                \
        int32x4 af0 = *(const int32x4*)(a_lds + (k_ * 2 + 0) * 1024 + sl_);    \
        int32x4 af1 = *(const int32x4*)(a_lds + (k_ * 2 + 1) * 1024 + sl_);    \
        acc0 = __builtin_amdgcn_mfma_i32_32x32x32_i8(af0, buf[j], acc0, 0, 0, 0); \
        acc1 = __builtin_amdgcn_mfma_i32_32x32x32_i8(af1, buf[j], acc1, 0, 0, 0); \
    }                                                                          \
} while (0)

__global__ __launch_bounds__(512, 4) void tern_gemm_kernel(const float* __restrict__ x,
                                                           const signed char* __restrict__ wqf,
                                                           float* __restrict__ out) {
    __shared__ __attribute__((aligned(16))) signed char a_lds[64 * 1024];
    const int tid = threadIdx.x;
    const long rowbase = (long)blockIdx.x * 64;

    // ---- Phase 1: stage + quantize x slab (64 rows x 1024 K) into
    //      fragment-order LDS. chunk c: row = c>>6, cir = c&63;
    //      k = cir>>1, ri = row>>5 ->
    //      addr = (k*2+ri)*1024 + (((cir&1)*32 + (row&31)) ^ (k&7))*16
    #pragma unroll
    for (int i = 0; i < 8; ++i) {
        int c   = tid + i * 512;   // chunk id 0..4095
        int row = c >> 6;          // 64 chunks per row
        int cir = c & 63;          // chunk-in-row
        const floatx4* src = (const floatx4*)(x + (rowbase + row) * 1024 + cir * 16);
        signed char q[16];
        #pragma unroll
        for (int j = 0; j < 4; ++j) {
            floatx4 f = __builtin_nontemporal_load(src + j);
            #pragma unroll
            for (int e = 0; e < 4; ++e)
                q[j * 4 + e] = (signed char)((f[e] >= THRESH) - (f[e] <= -THRESH));
        }
        int k    = cir >> 1;
        int blk  = k * 2 + (row >> 5);
        int slot = ((cir & 1) * 32 + (row & 31)) ^ (k & 7);
        *(int32x4*)(a_lds + blk * 1024 + slot * 16) = *(const int32x4*)q;
    }

    // ---- Phase 2: compute. Wave owns ONE 32-col tile per ot (4 ot). ----
    const int wave = tid >> 6;    // 0..7
    const int lane = tid & 63;
    const int l31  = lane & 31;
    const int hi   = lane >> 5;

    const signed char* bp0 = wqf + (size_t)wave * 32768 + lane * 16;

    // prologue: first burst (ot=0, k=0..3) issued BEFORE the barrier --
    // its L2 latency hides under the slowest wave's phase-1 tail.
    int32x4 bA[4], bB[4];
    LOADB(bA, bp0, 0);

    __syncthreads();

    for (int ot = 0; ot < 4; ++ot) {
        const signed char* bp  = bp0 + (size_t)ot * 8 * 32768;   // this tile
        const signed char* bpn = (ot == 3) ? bp0 : bp + 8 * 32768; // next tile
        const int nb = ot * 8 + wave;

        int32x16 acc0 = {0,0,0,0,0,0,0,0,0,0,0,0,0,0,0,0};  // rows  0..31
        int32x16 acc1 = acc0;                                 // rows 32..63

        // 8-step ping-pong: issue 4 loads into idle buffer, MFMA ready one.
        LOADB(bB, bp, 4);    COMPB(bA, 0);
        LOADB(bA, bp, 8);    COMPB(bB, 4);
        LOADB(bB, bp, 12);   COMPB(bA, 8);
        LOADB(bA, bp, 16);   COMPB(bB, 12);
        LOADB(bB, bp, 20);   COMPB(bA, 16);
        LOADB(bA, bp, 24);   COMPB(bB, 20);
        LOADB(bB, bp, 28);   COMPB(bA, 24);
        LOADB(bA, bpn, 0);   COMPB(bB, 28);   // next tile's burst in flight
                                              // across the epilogue below

        // ---- epilogue: scalar nt stores; per instr 64 lanes cover two
        //      contiguous 128 B row segments (rows rit, rit+4) ----
        const int cb = nb * 32 + l31;
        #pragma unroll
        for (int r = 0; r < 16; ++r) {
            const int rit = (r & 3) + 8 * (r >> 2) + 4 * hi;
            float* o0 = out + (rowbase + rit) * 1024 + cb;        // rows  0..31
            float* o1 = o0 + 32L * 1024;                          // rows 32..63
            __builtin_nontemporal_store((float)acc0[r], o0);
            __builtin_nontemporal_store((float)acc1[r], o1);
        }
    }
}

extern "C" void kernel_launch(void* const* d_in, const int* in_sizes, int n_in,
                              void* d_out, int out_size, void* d_ws, size_t ws_size,
                              hipStream_t stream) {
    const float* x = (const float*)d_in[0];      // [32768, 1024] fp32
    const float* w = (const float*)d_in[1];      // [1024, 1024] fp32
    float* out = (float*)d_out;                  // [32768, 1024] fp32
    signed char* wqf = (signed char*)d_ws;       // 1 MB int8 scratch (fragment order)

    quant_w_kernel<<<dim3(256), dim3(256), 0, stream>>>(w, wqf);
    // 32768 rows / 64 = 512 blocks (2 per CU), 8 waves each
    tern_gemm_kernel<<<dim3(512), dim3(512), 0, stream>>>(x, wqf, out);
}